// Round 3
// baseline (1804.522 us; speedup 1.0000x reference)
//
#include <hip/hip_runtime.h>
#include <stdint.h>
#include <stddef.h>

typedef int v4i  __attribute__((ext_vector_type(4)));
typedef int v16i __attribute__((ext_vector_type(16)));

#define KCH  256                 // K-chunk per LDS buffer (16 granules of 16 B)
#define BUFB (128 * 256)         // 32 KB per buffer: [row][slot] 16B units
#define LDSB (2 * BUFB)          // 64 KB; 512-thr blocks -> 2 blocks/CU = 4 waves/SIMD

// async global->LDS, 16B per lane.
__device__ __forceinline__ void gl_lds16(const uint8_t* g, uint8_t* l) {
    __builtin_amdgcn_global_load_lds(
        (const __attribute__((address_space(1))) uint32_t*)g,
        (__attribute__((address_space(3))) uint32_t*)l,
        16, 0, 0);
}

// Software q8: EXACT reference semantics (floor(log2), clamp[-6,8], half-even, sat 448).
__device__ __forceinline__ float q8f(float v) {
    float a = fabsf(v);
    int e = (int)(__float_as_uint(a) >> 23) - 127;
    e = e < -6 ? -6 : (e > 8 ? 8 : e);
    float step  = __uint_as_float((uint32_t)(e - 3 + 127) << 23);  // 2^(e-3)
    float rstep = __uint_as_float((uint32_t)(3 - e + 127) << 23);  // 2^(3-e)
    float q = fminf(rintf(a * rstep) * step, 448.0f);
    return v < 0.0f ? -q : q;
}
__device__ __forceinline__ int qm(float v) {  // q8 value * 512 (exact int)
    return (int)rintf(q8f(v) * 512.0f);
}

// integer round-half-even shift: RNE(a / 2^s), a >= 0, s >= 1
__device__ __forceinline__ uint32_t rne_sh(uint32_t a, int s) {
    uint32_t t = a >> s;
    uint32_t rem = a & ((1u << s) - 1u);
    uint32_t half = 1u << (s - 1);
    t += (rem > half) || (rem == half && (t & 1u));
    return t;
}

// Fused quant. x is written in PACKED fragment order:
//   addr(r,g,b) = ((r>>5)*(K/16) + g)*512 + (r&31)*16 + b   (K=1024, 64 granules)
// so the GEMM's A-loads are lane-linear 1KB bursts. w1/w2 stay row-major.
__global__ __launch_bounds__(256) void quant_all_kernel(
    const float* __restrict__ x,  uint32_t* __restrict__ xh, uint32_t* __restrict__ xl,
    const float* __restrict__ w1, uint32_t* __restrict__ w1m,
    const float* __restrict__ w2, uint32_t* __restrict__ w2m,
    int n4x, int n4w1, int n4w2) {
    int i = blockIdx.x * 256 + threadIdx.x;
    if (i < n4x) {
        float4 v = ((const float4*)x)[i];
        int m0 = qm(v.x), m1 = qm(v.y), m2 = qm(v.z), m3 = qm(v.w);
        uint32_t h = ((uint32_t)((m0 >> 5) & 0xff)) | ((uint32_t)((m1 >> 5) & 0xff) << 8) |
                     ((uint32_t)((m2 >> 5) & 0xff) << 16) | ((uint32_t)((m3 >> 5) & 0xff) << 24);
        uint32_t l = ((uint32_t)(m0 & 31)) | ((uint32_t)(m1 & 31) << 8) |
                     ((uint32_t)(m2 & 31) << 16) | ((uint32_t)(m3 & 31) << 24);
        int r = i >> 8, c4 = i & 255;                     // K/4 = 256 float4 per row
        int pi = ((r >> 5) * 64 + (c4 >> 2)) * 128 + (r & 31) * 4 + (c4 & 3);
        xh[pi] = h;
        xl[pi] = l;
    } else if (i < n4x + n4w1) {
        int j = i - n4x;
        float4 v = ((const float4*)w1)[j];
        w1m[j] = ((uint32_t)(qm(v.x) & 0xff)) | ((uint32_t)(qm(v.y) & 0xff) << 8) |
                 ((uint32_t)(qm(v.z) & 0xff) << 16) | ((uint32_t)(qm(v.w) & 0xff) << 24);
    } else if (i < n4x + n4w1 + n4w2) {
        int j = i - n4x - n4w1;
        float4 v = ((const float4*)w2)[j];
        w2m[j] = ((uint32_t)(qm(v.x) & 0xff)) | ((uint32_t)(qm(v.y) & 0xff) << 8) |
                 ((uint32_t)(qm(v.z) & 0xff) << 16) | ((uint32_t)(qm(v.w) & 0xff) << 24);
    }
}

// Stage one K-chunk of B (row-major) into LDS [row][slot], slot = g ^ (row&15).
// 8 waves, 4 insts each (32 total = 128 rows x 256B).
__device__ __forceinline__ void stage_chunk(
    const uint8_t* __restrict__ Bm, uint8_t* dst,
    int bn, int K, int kc, int wave, int lane) {
    const int r0 = lane >> 4;
    const int sl = lane & 15;
#pragma unroll
    for (int s = 0; s < 4; ++s) {
        const int qd  = wave * 4 + s;
        const int row = qd * 4 + r0;
        const int g   = sl ^ (row & 15);
        gl_lds16(Bm + (size_t)(bn * 128 + row) * K + kc + g * 16,
                 dst + qd * 1024 + lane * 16);
    }
}

// C = (32*Ah + Al) * Bm^T * 2^-18, exact i32 via mfma_i32_32x32x32_i8.
// A is PACKED (fragment-order): per-t load = base + t*1024 + lane*16 (lane-linear).
// 512 thr = 8 waves, block tile 256x128, wave tile 32x128, 2 blocks/CU
// -> 16 waves/CU = 4 waves/SIMD (round-3 change: occupancy 2->4 waves/SIMD;
// the 90us baseline was latency-bound at 2 waves/SIMD, MfmaUtil 33%).
// B-tile now reused over 256 A-rows per block (B traffic halves).
//
// 1-D grid, XCD swizzle: xcd = bid&7 (dispatch round-robin), bm-group of 4
// pinned per XCD (A working set 4 x 512KB = 2MB, L2-resident), bn sweeps.
//   bm = (bid&7)*4 + (bid>>3)&3,  bn = bid>>5.   Bijective for 1024/256 blocks.
//
// EPI=0: q8+ReLU -> hi/lo planes written PACKED (K=N for next layer). EPI=1: fp32 row-major.
template <int EPI>
__global__ __launch_bounds__(512, 4) void gemm_i8_big(
    const uint8_t* __restrict__ Ah, const uint8_t* __restrict__ Al,
    const uint8_t* __restrict__ Bm,
    void* __restrict__ Ch, void* __restrict__ Cl,
    int M, int N, int K) {
    extern __shared__ uint8_t sB[];  // 2 x BUFB

    const int tid  = threadIdx.x;
    const int lane = tid & 63;
    const int wave = tid >> 6;     // 8 waves = 8 row strips
    const int col  = lane & 31;
    const int kh   = lane >> 5;
    const int xm   = col & 15;

    const int bid = blockIdx.x;
    const int bm  = ((bid & 7) << 2) | ((bid >> 3) & 3);
    const int bn  = bid >> 5;

    v16i acc[2][4];
#pragma unroll
    for (int p = 0; p < 2; ++p)
#pragma unroll
        for (int j = 0; j < 4; ++j) acc[p][j] = (v16i)0;

    // packed A: row-block (bm*8 + wave), sequential 1KB per t-step across all K
    const size_t abase = (size_t)(bm * 8 + wave) * (K >> 4) * 512 + lane * 16;
    const uint8_t* pAh = Ah + abase;
    const uint8_t* pAl = Al + abase;
    const int NT = K >> 5;         // total t-steps (1KB each)

    int rowoff[4];
#pragma unroll
    for (int j = 0; j < 4; ++j) rowoff[j] = (j * 32 + col) * 256;

    const int NC = K / KCH;
    stage_chunk(Bm, sB, bn, K, 0, wave, lane);

    // preload first A step
    v4i a0 = *(const v4i*)(pAh);
    v4i a1 = *(const v4i*)(pAl);

    for (int c = 0; c < NC; ++c) {
        __syncthreads();  // stage(c) complete
        if (c + 1 < NC)
            stage_chunk(Bm, sB + ((c + 1) & 1) * BUFB, bn, K, (c + 1) * KCH, wave, lane);

        const uint8_t* buf = sB + (c & 1) * BUFB;
#pragma unroll
        for (int t = 0; t < 8; ++t) {
            const int gt = c * 8 + t;
            v4i na0 = a0, na1 = a1;
            if (gt + 1 < NT) {  // wave-uniform; sequential 1KB prefetch
                na0 = *(const v4i*)(pAh + (size_t)(gt + 1) * 1024);
                na1 = *(const v4i*)(pAl + (size_t)(gt + 1) * 1024);
            }
            const int slot = ((2 * t + kh) & 15) ^ xm;
            v4i b[4];
#pragma unroll
            for (int j = 0; j < 4; ++j)
                b[j] = *(const v4i*)(buf + rowoff[j] + slot * 16);
#pragma unroll
            for (int j = 0; j < 4; ++j) {
                acc[0][j] = __builtin_amdgcn_mfma_i32_32x32x32_i8(a0, b[j], acc[0][j], 0, 0, 0);
                acc[1][j] = __builtin_amdgcn_mfma_i32_32x32x32_i8(a1, b[j], acc[1][j], 0, 0, 0);
            }
            a0 = na0; a1 = na1;
        }
    }

    // C/D layout (32x32): col = lane&31, row = (reg&3) + 8*(reg>>2) + 4*(lane>>5)
    const int Gn = N >> 4;  // granules per output row (packed dest, EPI=0)
    const int rb = bm * 8 + wave;
#pragma unroll
    for (int j = 0; j < 4; ++j) {
        const int colk = bn * 128 + j * 32 + col;
#pragma unroll
        for (int reg = 0; reg < 16; ++reg) {
            int mt = acc[0][j][reg] * 32 + acc[1][j][reg];  // exact, |mt| < 2^24
            const int rw = 4 * kh + (reg & 3) + 8 * (reg >> 2);  // row within 32
            if (EPI == 0) {
                uint8_t hb = 0, lb = 0;
                if (mt > 0) {
                    int s = 28 - __builtin_clz((uint32_t)mt);
                    if (s < 9) s = 9;
                    int mh = (int)(rne_sh((uint32_t)mt, s) << (s - 9));
                    hb = (uint8_t)(mh >> 5);
                    lb = (uint8_t)(mh & 31);
                }
                size_t pa = ((size_t)rb * Gn + (colk >> 4)) * 512 + rw * 16 + (colk & 15);
                ((uint8_t*)Ch)[pa] = hb;
                ((uint8_t*)Cl)[pa] = lb;
            } else {
                uint32_t a = mt < 0 ? (uint32_t)(-mt) : (uint32_t)mt;
                float v = 0.0f;
                if (a) {
                    int s = 28 - __builtin_clz(a);
                    if (s < 9) s = 9;
                    v = (float)(rne_sh(a, s) << s) * 0x1p-18f;  // exact
                    if (mt < 0) v = -v;
                }
                ((float*)Ch)[(size_t)(rb * 32 + rw) * N + colk] = v;
            }
        }
    }
}

extern "C" void kernel_launch(void* const* d_in, const int* in_sizes, int n_in,
                              void* d_out, int out_size, void* d_ws, size_t ws_size,
                              hipStream_t stream) {
    const int Bsz = 8192, DIN = 1024, DH = 4096, DOUT = 1024;
    const float* x  = (const float*)d_in[0];
    const float* w1 = (const float*)d_in[1];
    const float* w2 = (const float*)d_in[2];
    float* out = (float*)d_out;

    uint8_t* ws  = (uint8_t*)d_ws;
    uint8_t* xh  = ws;                            //  8 MB (packed)
    uint8_t* xl  = xh  + (size_t)Bsz * DIN;       //  8 MB (packed)
    uint8_t* w1m = xl  + (size_t)Bsz * DIN;       //  4 MB
    uint8_t* w2m = w1m + (size_t)DH  * DIN;       //  4 MB
    uint8_t* hh  = w2m + (size_t)DOUT * DH;       // 32 MB (packed)
    uint8_t* hl  = hh  + (size_t)Bsz * DH;        // 32 MB (packed)

    static bool attr_done = false;
    if (!attr_done) {
        hipFuncSetAttribute((const void*)gemm_i8_big<0>,
                            hipFuncAttributeMaxDynamicSharedMemorySize, LDSB);
        hipFuncSetAttribute((const void*)gemm_i8_big<1>,
                            hipFuncAttributeMaxDynamicSharedMemorySize, LDSB);
        attr_done = true;
    }

    const int n4x = Bsz * DIN / 4, n4w1 = DH * DIN / 4, n4w2 = DOUT * DH / 4;
    quant_all_kernel<<<(n4x + n4w1 + n4w2) / 256, 256, 0, stream>>>(
        x, (uint32_t*)xh, (uint32_t*)xl, w1, (uint32_t*)w1m, w2, (uint32_t*)w2m,
        n4x, n4w1, n4w2);

    // fc1: h = relu(q8(x8 @ w1q^T)) -> packed hi/lo  [8192,4096]
    // grid = (8192/256) x (4096/128) = 32 x 32 = 1024 blocks
    gemm_i8_big<0><<<dim3(1024), 512, LDSB, stream>>>(xh, xl, w1m, (void*)hh, (void*)hl, Bsz, DH, DIN);

    // fc2: out = q8(h @ w2q^T)  [8192,1024] fp32
    // grid = 32 x 8 = 256 blocks
    gemm_i8_big<1><<<dim3(256), 512, LDSB, stream>>>(hh, hl, w2m, (void*)out, nullptr, Bsz, DOUT, DH);
}

// Round 4
// 265.689 us; speedup vs baseline: 6.7918x; 6.7918x over previous
//
#include <hip/hip_runtime.h>
#include <stdint.h>
#include <stddef.h>

typedef int v4i  __attribute__((ext_vector_type(4)));
typedef int v16i __attribute__((ext_vector_type(16)));

#define KCH  256                 // K-chunk per LDS buffer (16 granules of 16 B)
#define BUFB (128 * 256)         // 32 KB per buffer: [row][slot] 16B units
#define LDSB (2 * BUFB)          // 64 KB -> 2 blocks/CU (512 thr) = 4 waves/SIMD

// async global->LDS, 16B per lane.
__device__ __forceinline__ void gl_lds16(const uint8_t* g, uint8_t* l) {
    __builtin_amdgcn_global_load_lds(
        (const __attribute__((address_space(1))) uint32_t*)g,
        (__attribute__((address_space(3))) uint32_t*)l,
        16, 0, 0);
}

// Software q8: EXACT reference semantics (floor(log2), clamp[-6,8], half-even, sat 448).
__device__ __forceinline__ float q8f(float v) {
    float a = fabsf(v);
    int e = (int)(__float_as_uint(a) >> 23) - 127;
    e = e < -6 ? -6 : (e > 8 ? 8 : e);
    float step  = __uint_as_float((uint32_t)(e - 3 + 127) << 23);  // 2^(e-3)
    float rstep = __uint_as_float((uint32_t)(3 - e + 127) << 23);  // 2^(3-e)
    float q = fminf(rintf(a * rstep) * step, 448.0f);
    return v < 0.0f ? -q : q;
}
__device__ __forceinline__ int qm(float v) {  // q8 value * 512 (exact int)
    return (int)rintf(q8f(v) * 512.0f);
}

// integer round-half-even shift: RNE(a / 2^s), a >= 0, s >= 1
__device__ __forceinline__ uint32_t rne_sh(uint32_t a, int s) {
    uint32_t t = a >> s;
    uint32_t rem = a & ((1u << s) - 1u);
    uint32_t half = 1u << (s - 1);
    t += (rem > half) || (rem == half && (t & 1u));
    return t;
}

// Fused quant. x is written in PACKED fragment order:
//   addr(r,g,b) = ((r>>5)*(K/16) + g)*512 + (r&31)*16 + b   (K=1024, 64 granules)
// so the GEMM's A-loads are lane-linear 1KB bursts. w1/w2 stay row-major.
__global__ __launch_bounds__(256) void quant_all_kernel(
    const float* __restrict__ x,  uint32_t* __restrict__ xh, uint32_t* __restrict__ xl,
    const float* __restrict__ w1, uint32_t* __restrict__ w1m,
    const float* __restrict__ w2, uint32_t* __restrict__ w2m,
    int n4x, int n4w1, int n4w2) {
    int i = blockIdx.x * 256 + threadIdx.x;
    if (i < n4x) {
        float4 v = ((const float4*)x)[i];
        int m0 = qm(v.x), m1 = qm(v.y), m2 = qm(v.z), m3 = qm(v.w);
        uint32_t h = ((uint32_t)((m0 >> 5) & 0xff)) | ((uint32_t)((m1 >> 5) & 0xff) << 8) |
                     ((uint32_t)((m2 >> 5) & 0xff) << 16) | ((uint32_t)((m3 >> 5) & 0xff) << 24);
        uint32_t l = ((uint32_t)(m0 & 31)) | ((uint32_t)(m1 & 31) << 8) |
                     ((uint32_t)(m2 & 31) << 16) | ((uint32_t)(m3 & 31) << 24);
        int r = i >> 8, c4 = i & 255;                     // K/4 = 256 float4 per row
        int pi = ((r >> 5) * 64 + (c4 >> 2)) * 128 + (r & 31) * 4 + (c4 & 3);
        xh[pi] = h;
        xl[pi] = l;
    } else if (i < n4x + n4w1) {
        int j = i - n4x;
        float4 v = ((const float4*)w1)[j];
        w1m[j] = ((uint32_t)(qm(v.x) & 0xff)) | ((uint32_t)(qm(v.y) & 0xff) << 8) |
                 ((uint32_t)(qm(v.z) & 0xff) << 16) | ((uint32_t)(qm(v.w) & 0xff) << 24);
    } else if (i < n4x + n4w1 + n4w2) {
        int j = i - n4x - n4w1;
        float4 v = ((const float4*)w2)[j];
        w2m[j] = ((uint32_t)(qm(v.x) & 0xff)) | ((uint32_t)(qm(v.y) & 0xff) << 8) |
                 ((uint32_t)(qm(v.z) & 0xff) << 16) | ((uint32_t)(qm(v.w) & 0xff) << 24);
    }
}

// Stage one K-chunk of B (row-major) into LDS [row][slot], slot = g ^ (row&15).
// 8 waves, 4 insts each (32 total = 128 rows x 256 B).
__device__ __forceinline__ void stage_chunk(
    const uint8_t* __restrict__ Bm, uint8_t* dst,
    int bn, int K, int kc, int wave, int lane) {
    const int r0 = lane >> 4;
    const int sl = lane & 15;
#pragma unroll
    for (int s = 0; s < 4; ++s) {
        const int qd  = wave * 4 + s;
        const int row = qd * 4 + r0;
        const int g   = sl ^ (row & 15);
        gl_lds16(Bm + (size_t)(bn * 128 + row) * K + kc + g * 16,
                 dst + qd * 1024 + lane * 16);
    }
}

// C = (32*Ah + Al) * Bm^T * 2^-18, exact i32 via mfma_i32_32x32x32_i8.
// A is PACKED (fragment-order): per-t load = base + t*1024 + lane*16 (lane-linear).
//
// Round-4 structure: 512 thr = 8 waves, block tile 128x128, wave tile 32x64
// (wr = wave>>1 row strip, wc = wave&1 column half). acc = 2 planes x 2 x v16i
// = 64 AGPR/wave (vs 128 in the 4-wave layout) -> total regs ~<=128/wave, so
// __launch_bounds__(512,4) holds 2 blocks/CU = 16 waves/CU = 4 waves/SIMD
// (round 0 was register-capped at 2 waves/SIMD: 108 VGPR + 128 AGPR = 236).
// Per-CU work per t-step identical to round 0; A loads 2x redundant (L1-served).
//
// 1-D grid, XCD swizzle (same as round 1, bijective for 2048/512 blocks):
//   bm = (bid&7)*8 + (bid>>3)&7,  bn = (bid>>9)*8 + (bid>>6)&7
//
// EPI=0: q8+ReLU -> hi/lo planes written PACKED (K=N for next layer). EPI=1: fp32 row-major.
template <int EPI>
__global__ __launch_bounds__(512, 4) void gemm_i8_big(
    const uint8_t* __restrict__ Ah, const uint8_t* __restrict__ Al,
    const uint8_t* __restrict__ Bm,
    void* __restrict__ Ch, void* __restrict__ Cl,
    int M, int N, int K) {
    extern __shared__ uint8_t sB[];  // 2 x BUFB

    const int tid  = threadIdx.x;
    const int lane = tid & 63;
    const int wave = tid >> 6;     // 8 waves
    const int wr   = wave >> 1;    // row strip (32 rows)
    const int wc   = wave & 1;     // column half (64 cols)
    const int col  = lane & 31;
    const int kh   = lane >> 5;
    const int xm   = col & 15;

    const int bid = blockIdx.x;
    const int bm  = ((bid & 7) << 3) | ((bid >> 3) & 7);
    const int bn  = (((bid >> 9) << 3) | ((bid >> 6) & 7));

    v16i acc[2][2];
#pragma unroll
    for (int p = 0; p < 2; ++p)
#pragma unroll
        for (int j = 0; j < 2; ++j) acc[p][j] = (v16i)0;

    // packed A: row-block (bm*4 + wr), sequential 1KB per t-step across all K
    const size_t abase = (size_t)(bm * 4 + wr) * (K >> 4) * 512 + lane * 16;
    const uint8_t* pAh = Ah + abase;
    const uint8_t* pAl = Al + abase;
    const int NT = K >> 5;         // total t-steps (1KB each)

    int rowoff[2];
#pragma unroll
    for (int j = 0; j < 2; ++j) rowoff[j] = (wc * 64 + j * 32 + col) * 256;

    const int NC = K / KCH;
    stage_chunk(Bm, sB, bn, K, 0, wave, lane);

    // preload first A step
    v4i a0 = *(const v4i*)(pAh);
    v4i a1 = *(const v4i*)(pAl);

    for (int c = 0; c < NC; ++c) {
        __syncthreads();  // stage(c) complete
        if (c + 1 < NC)
            stage_chunk(Bm, sB + ((c + 1) & 1) * BUFB, bn, K, (c + 1) * KCH, wave, lane);

        const uint8_t* buf = sB + (c & 1) * BUFB;
#pragma unroll
        for (int t = 0; t < 8; ++t) {
            const int gt = c * 8 + t;
            v4i na0 = a0, na1 = a1;
            if (gt + 1 < NT) {  // wave-uniform; sequential 1KB prefetch
                na0 = *(const v4i*)(pAh + (size_t)(gt + 1) * 1024);
                na1 = *(const v4i*)(pAl + (size_t)(gt + 1) * 1024);
            }
            const int slot = ((2 * t + kh) & 15) ^ xm;
            v4i b[2];
#pragma unroll
            for (int j = 0; j < 2; ++j)
                b[j] = *(const v4i*)(buf + rowoff[j] + slot * 16);
#pragma unroll
            for (int j = 0; j < 2; ++j) {
                acc[0][j] = __builtin_amdgcn_mfma_i32_32x32x32_i8(a0, b[j], acc[0][j], 0, 0, 0);
                acc[1][j] = __builtin_amdgcn_mfma_i32_32x32x32_i8(a1, b[j], acc[1][j], 0, 0, 0);
            }
            a0 = na0; a1 = na1;
        }
    }

    // C/D layout (32x32): col = lane&31, row = (reg&3) + 8*(reg>>2) + 4*(lane>>5)
    const int Gn = N >> 4;  // granules per output row (packed dest, EPI=0)
    const int rb = bm * 4 + wr;
#pragma unroll
    for (int j = 0; j < 2; ++j) {
        const int colk = bn * 128 + wc * 64 + j * 32 + col;
#pragma unroll
        for (int reg = 0; reg < 16; ++reg) {
            int mt = acc[0][j][reg] * 32 + acc[1][j][reg];  // exact, |mt| < 2^24
            const int rw = 4 * kh + (reg & 3) + 8 * (reg >> 2);  // row within 32
            if (EPI == 0) {
                uint8_t hb = 0, lb = 0;
                if (mt > 0) {
                    int s = 28 - __builtin_clz((uint32_t)mt);
                    if (s < 9) s = 9;
                    int mh = (int)(rne_sh((uint32_t)mt, s) << (s - 9));
                    hb = (uint8_t)(mh >> 5);
                    lb = (uint8_t)(mh & 31);
                }
                size_t pa = ((size_t)rb * Gn + (colk >> 4)) * 512 + rw * 16 + (colk & 15);
                ((uint8_t*)Ch)[pa] = hb;
                ((uint8_t*)Cl)[pa] = lb;
            } else {
                uint32_t a = mt < 0 ? (uint32_t)(-mt) : (uint32_t)mt;
                float v = 0.0f;
                if (a) {
                    int s = 28 - __builtin_clz(a);
                    if (s < 9) s = 9;
                    v = (float)(rne_sh(a, s) << s) * 0x1p-18f;  // exact
                    if (mt < 0) v = -v;
                }
                ((float*)Ch)[(size_t)(rb * 32 + rw) * N + colk] = v;
            }
        }
    }
}

extern "C" void kernel_launch(void* const* d_in, const int* in_sizes, int n_in,
                              void* d_out, int out_size, void* d_ws, size_t ws_size,
                              hipStream_t stream) {
    const int Bsz = 8192, DIN = 1024, DH = 4096, DOUT = 1024;
    const float* x  = (const float*)d_in[0];
    const float* w1 = (const float*)d_in[1];
    const float* w2 = (const float*)d_in[2];
    float* out = (float*)d_out;

    uint8_t* ws  = (uint8_t*)d_ws;
    uint8_t* xh  = ws;                            //  8 MB (packed)
    uint8_t* xl  = xh  + (size_t)Bsz * DIN;       //  8 MB (packed)
    uint8_t* w1m = xl  + (size_t)Bsz * DIN;       //  4 MB
    uint8_t* w2m = w1m + (size_t)DH  * DIN;       //  4 MB
    uint8_t* hh  = w2m + (size_t)DOUT * DH;       // 32 MB (packed)
    uint8_t* hl  = hh  + (size_t)Bsz * DH;        // 32 MB (packed)

    static bool attr_done = false;
    if (!attr_done) {
        hipFuncSetAttribute((const void*)gemm_i8_big<0>,
                            hipFuncAttributeMaxDynamicSharedMemorySize, LDSB);
        hipFuncSetAttribute((const void*)gemm_i8_big<1>,
                            hipFuncAttributeMaxDynamicSharedMemorySize, LDSB);
        attr_done = true;
    }

    const int n4x = Bsz * DIN / 4, n4w1 = DH * DIN / 4, n4w2 = DOUT * DH / 4;
    quant_all_kernel<<<(n4x + n4w1 + n4w2) / 256, 256, 0, stream>>>(
        x, (uint32_t*)xh, (uint32_t*)xl, w1, (uint32_t*)w1m, w2, (uint32_t*)w2m,
        n4x, n4w1, n4w2);

    // fc1: h = relu(q8(x8 @ w1q^T)) -> packed hi/lo  [8192,4096]
    // grid = (8192/128) x (4096/128) = 64 x 32 = 2048 blocks of 512 thr
    gemm_i8_big<0><<<dim3(2048), 512, LDSB, stream>>>(xh, xl, w1m, (void*)hh, (void*)hl, Bsz, DH, DIN);

    // fc2: out = q8(h @ w2q^T)  [8192,1024] fp32
    // grid = 64 x 8 = 512 blocks of 512 thr
    gemm_i8_big<1><<<dim3(512), 512, LDSB, stream>>>(hh, hl, w2m, (void*)out, nullptr, Bsz, DOUT, DH);
}

// Round 5
// 255.159 us; speedup vs baseline: 7.0722x; 1.0413x over previous
//
#include <hip/hip_runtime.h>
#include <stdint.h>
#include <stddef.h>

typedef int v4i  __attribute__((ext_vector_type(4)));
typedef int v16i __attribute__((ext_vector_type(16)));

#define KCH  256                 // K-chunk per LDS buffer (16 granules of 16 B)
#define BUFB (128 * 256)         // 32 KB per buffer: [row][slot] 16B units
#define LDSB (2 * BUFB)          // 64 KB -> 2 blocks/CU

// async global->LDS, 16B per lane.
__device__ __forceinline__ void gl_lds16(const uint8_t* g, uint8_t* l) {
    __builtin_amdgcn_global_load_lds(
        (const __attribute__((address_space(1))) uint32_t*)g,
        (__attribute__((address_space(3))) uint32_t*)l,
        16, 0, 0);
}

// Software q8: EXACT reference semantics (floor(log2), clamp[-6,8], half-even, sat 448).
__device__ __forceinline__ float q8f(float v) {
    float a = fabsf(v);
    int e = (int)(__float_as_uint(a) >> 23) - 127;
    e = e < -6 ? -6 : (e > 8 ? 8 : e);
    float step  = __uint_as_float((uint32_t)(e - 3 + 127) << 23);  // 2^(e-3)
    float rstep = __uint_as_float((uint32_t)(3 - e + 127) << 23);  // 2^(3-e)
    float q = fminf(rintf(a * rstep) * step, 448.0f);
    return v < 0.0f ? -q : q;
}
__device__ __forceinline__ int qm(float v) {  // q8 value * 512 (exact int)
    return (int)rintf(q8f(v) * 512.0f);
}

// integer round-half-even shift: RNE(a / 2^s), a >= 0, s >= 1
__device__ __forceinline__ uint32_t rne_sh(uint32_t a, int s) {
    uint32_t t = a >> s;
    uint32_t rem = a & ((1u << s) - 1u);
    uint32_t half = 1u << (s - 1);
    t += (rem > half) || (rem == half && (t & 1u));
    return t;
}

// Fused quant. x is written in PACKED fragment order:
//   addr(r,g,b) = ((r>>5)*(K/16) + g)*512 + (r&31)*16 + b   (K=1024, 64 granules)
// so the GEMM's A-loads are lane-linear 1KB bursts. w1/w2 stay row-major.
__global__ __launch_bounds__(256) void quant_all_kernel(
    const float* __restrict__ x,  uint32_t* __restrict__ xh, uint32_t* __restrict__ xl,
    const float* __restrict__ w1, uint32_t* __restrict__ w1m,
    const float* __restrict__ w2, uint32_t* __restrict__ w2m,
    int n4x, int n4w1, int n4w2) {
    int i = blockIdx.x * 256 + threadIdx.x;
    if (i < n4x) {
        float4 v = ((const float4*)x)[i];
        int m0 = qm(v.x), m1 = qm(v.y), m2 = qm(v.z), m3 = qm(v.w);
        uint32_t h = ((uint32_t)((m0 >> 5) & 0xff)) | ((uint32_t)((m1 >> 5) & 0xff) << 8) |
                     ((uint32_t)((m2 >> 5) & 0xff) << 16) | ((uint32_t)((m3 >> 5) & 0xff) << 24);
        uint32_t l = ((uint32_t)(m0 & 31)) | ((uint32_t)(m1 & 31) << 8) |
                     ((uint32_t)(m2 & 31) << 16) | ((uint32_t)(m3 & 31) << 24);
        int r = i >> 8, c4 = i & 255;                     // K/4 = 256 float4 per row
        int pi = ((r >> 5) * 64 + (c4 >> 2)) * 128 + (r & 31) * 4 + (c4 & 3);
        xh[pi] = h;
        xl[pi] = l;
    } else if (i < n4x + n4w1) {
        int j = i - n4x;
        float4 v = ((const float4*)w1)[j];
        w1m[j] = ((uint32_t)(qm(v.x) & 0xff)) | ((uint32_t)(qm(v.y) & 0xff) << 8) |
                 ((uint32_t)(qm(v.z) & 0xff) << 16) | ((uint32_t)(qm(v.w) & 0xff) << 24);
    } else if (i < n4x + n4w1 + n4w2) {
        int j = i - n4x - n4w1;
        float4 v = ((const float4*)w2)[j];
        w2m[j] = ((uint32_t)(qm(v.x) & 0xff)) | ((uint32_t)(qm(v.y) & 0xff) << 8) |
                 ((uint32_t)(qm(v.z) & 0xff) << 16) | ((uint32_t)(qm(v.w) & 0xff) << 24);
    }
}

// Stage one K-chunk of B (row-major) into LDS [row][slot], slot = g ^ (row&15).
// Per inst: 4 consecutive rows, 16 fully-used lines. 4 waves, 8 insts each.
__device__ __forceinline__ void stage_chunk(
    const uint8_t* __restrict__ Bm, uint8_t* dst,
    int bn, int K, int kc, int wave, int lane) {
    const int r0 = lane >> 4;
    const int sl = lane & 15;
#pragma unroll
    for (int s = 0; s < 8; ++s) {
        const int qd  = wave * 8 + s;
        const int row = qd * 4 + r0;
        const int g   = sl ^ (row & 15);
        gl_lds16(Bm + (size_t)(bn * 128 + row) * K + kc + g * 16,
                 dst + qd * 1024 + lane * 16);
    }
}

// C = (32*Ah + Al) * Bm^T * 2^-18, exact i32 via mfma_i32_32x32x32_i8.
// A is PACKED (fragment-order): per-t load = base + t*1024 + lane*16 (lane-linear).
// 256 thr = 4 waves, block tile 128x128, wave tile 32x128, 2 blocks/CU.
//
// Round-5 K-loop: HALF-CHUNK A BURSTS instead of 1-deep per-t prefetch.
// Rationale: vmcnt is an ordered FIFO counter; with per-t prefetch, consuming
// an A pair (vmcnt(2)) transitively forces retirement of the stage gl_lds
// issued 1-2 t-steps earlier -> exposed DMA latency every chunk for every
// wave (occupancy-independent 33% plateau, rounds 0/1/4). Now: burst A(t0..3)
// BEFORE the gl_lds, burst A(t4..7) after half-0 -> A consumes never drain
// gl_lds with <4 t-steps slack (~2300 cyc cover vs ~600), and A exposes only
// 2 pipelined head-latencies per chunk. Regs: +32 VGPR (ab[8]) -> ~252 total
// with 128 AGPR acc, fits launch_bounds(256,2) cap 256 without spill.
//
// 1-D grid, XCD swizzle (bijective for 2048/512 blocks):
//   bm = (bid&7)*8 + (bid>>3)&7,  bn = (bid>>9)*8 + (bid>>6)&7
//
// EPI=0: q8+ReLU -> hi/lo planes written PACKED (K=N for next layer). EPI=1: fp32 row-major.
template <int EPI>
__global__ __launch_bounds__(256, 2) void gemm_i8_big(
    const uint8_t* __restrict__ Ah, const uint8_t* __restrict__ Al,
    const uint8_t* __restrict__ Bm,
    void* __restrict__ Ch, void* __restrict__ Cl,
    int M, int N, int K) {
    extern __shared__ uint8_t sB[];  // 2 x BUFB

    const int tid  = threadIdx.x;
    const int lane = tid & 63;
    const int wave = tid >> 6;     // 4 waves = 4 row strips
    const int col  = lane & 31;
    const int kh   = lane >> 5;
    const int xm   = col & 15;

    const int bid = blockIdx.x;
    const int bm  = ((bid & 7) << 3) | ((bid >> 3) & 7);
    const int bn  = (((bid >> 9) << 3) | ((bid >> 6) & 7));

    v16i acc[2][4];
#pragma unroll
    for (int p = 0; p < 2; ++p)
#pragma unroll
        for (int j = 0; j < 4; ++j) acc[p][j] = (v16i)0;

    // packed A: row-block (bm*4 + wave), sequential 1KB per t-step across all K
    const size_t abase = (size_t)(bm * 4 + wave) * (K >> 4) * 512 + lane * 16;
    const uint8_t* pAh = Ah + abase;
    const uint8_t* pAl = Al + abase;

    int rowoff[4];
#pragma unroll
    for (int j = 0; j < 4; ++j) rowoff[j] = (j * 32 + col) * 256;

    const int NC = K / KCH;
    stage_chunk(Bm, sB, bn, K, 0, wave, lane);

    for (int c = 0; c < NC; ++c) {
        __syncthreads();  // stage(c) complete; all outstanding vmem had >=half-chunk slack
        const uint8_t* buf  = sB + (c & 1) * BUFB;
        const uint8_t* pAhc = pAh + (size_t)c * 8192;   // 8 t-steps x 1KB
        const uint8_t* pAlc = pAl + (size_t)c * 8192;

        v4i ab[8];
        // burst 0: A pairs for t = 0..3, issued BEFORE the staging gl_lds
#pragma unroll
        for (int u = 0; u < 4; ++u) {
            ab[2 * u]     = *(const v4i*)(pAhc + u * 1024);
            ab[2 * u + 1] = *(const v4i*)(pAlc + u * 1024);
        }
        if (c + 1 < NC)
            stage_chunk(Bm, sB + ((c + 1) & 1) * BUFB, bn, K, (c + 1) * KCH, wave, lane);

        // half 0: t = 0..3
#pragma unroll
        for (int u = 0; u < 4; ++u) {
            const int t = u;
            const int slot = ((2 * t + kh) & 15) ^ xm;
            v4i b[4];
#pragma unroll
            for (int j = 0; j < 4; ++j)
                b[j] = *(const v4i*)(buf + rowoff[j] + slot * 16);
#pragma unroll
            for (int j = 0; j < 4; ++j) {
                acc[0][j] = __builtin_amdgcn_mfma_i32_32x32x32_i8(ab[2 * u],     b[j], acc[0][j], 0, 0, 0);
                acc[1][j] = __builtin_amdgcn_mfma_i32_32x32x32_i8(ab[2 * u + 1], b[j], acc[1][j], 0, 0, 0);
            }
        }

        // burst 1: A pairs for t = 4..7 (after gl_lds in FIFO -> consuming them
        // forces gl_lds retirement only with ~4 t-steps of cover)
#pragma unroll
        for (int u = 0; u < 4; ++u) {
            ab[2 * u]     = *(const v4i*)(pAhc + (4 + u) * 1024);
            ab[2 * u + 1] = *(const v4i*)(pAlc + (4 + u) * 1024);
        }

        // half 1: t = 4..7
#pragma unroll
        for (int u = 0; u < 4; ++u) {
            const int t = 4 + u;
            const int slot = ((2 * t + kh) & 15) ^ xm;
            v4i b[4];
#pragma unroll
            for (int j = 0; j < 4; ++j)
                b[j] = *(const v4i*)(buf + rowoff[j] + slot * 16);
#pragma unroll
            for (int j = 0; j < 4; ++j) {
                acc[0][j] = __builtin_amdgcn_mfma_i32_32x32x32_i8(ab[2 * u],     b[j], acc[0][j], 0, 0, 0);
                acc[1][j] = __builtin_amdgcn_mfma_i32_32x32x32_i8(ab[2 * u + 1], b[j], acc[1][j], 0, 0, 0);
            }
        }
    }

    // C/D layout (32x32): col = lane&31, row = (reg&3) + 8*(reg>>2) + 4*(lane>>5)
    const int Gn = N >> 4;  // granules per output row (packed dest, EPI=0)
    const int rb = bm * 4 + wave;
#pragma unroll
    for (int j = 0; j < 4; ++j) {
        const int colk = bn * 128 + j * 32 + col;
#pragma unroll
        for (int reg = 0; reg < 16; ++reg) {
            int mt = acc[0][j][reg] * 32 + acc[1][j][reg];  // exact, |mt| < 2^24
            const int rw = 4 * kh + (reg & 3) + 8 * (reg >> 2);  // row within 32
            if (EPI == 0) {
                uint8_t hb = 0, lb = 0;
                if (mt > 0) {
                    int s = 28 - __builtin_clz((uint32_t)mt);
                    if (s < 9) s = 9;
                    int mh = (int)(rne_sh((uint32_t)mt, s) << (s - 9));
                    hb = (uint8_t)(mh >> 5);
                    lb = (uint8_t)(mh & 31);
                }
                size_t pa = ((size_t)rb * Gn + (colk >> 4)) * 512 + rw * 16 + (colk & 15);
                ((uint8_t*)Ch)[pa] = hb;
                ((uint8_t*)Cl)[pa] = lb;
            } else {
                uint32_t a = mt < 0 ? (uint32_t)(-mt) : (uint32_t)mt;
                float v = 0.0f;
                if (a) {
                    int s = 28 - __builtin_clz(a);
                    if (s < 9) s = 9;
                    v = (float)(rne_sh(a, s) << s) * 0x1p-18f;  // exact
                    if (mt < 0) v = -v;
                }
                ((float*)Ch)[(size_t)(rb * 32 + rw) * N + colk] = v;
            }
        }
    }
}

extern "C" void kernel_launch(void* const* d_in, const int* in_sizes, int n_in,
                              void* d_out, int out_size, void* d_ws, size_t ws_size,
                              hipStream_t stream) {
    const int Bsz = 8192, DIN = 1024, DH = 4096, DOUT = 1024;
    const float* x  = (const float*)d_in[0];
    const float* w1 = (const float*)d_in[1];
    const float* w2 = (const float*)d_in[2];
    float* out = (float*)d_out;

    uint8_t* ws  = (uint8_t*)d_ws;
    uint8_t* xh  = ws;                            //  8 MB (packed)
    uint8_t* xl  = xh  + (size_t)Bsz * DIN;       //  8 MB (packed)
    uint8_t* w1m = xl  + (size_t)Bsz * DIN;       //  4 MB
    uint8_t* w2m = w1m + (size_t)DH  * DIN;       //  4 MB
    uint8_t* hh  = w2m + (size_t)DOUT * DH;       // 32 MB (packed)
    uint8_t* hl  = hh  + (size_t)Bsz * DH;        // 32 MB (packed)

    static bool attr_done = false;
    if (!attr_done) {
        hipFuncSetAttribute((const void*)gemm_i8_big<0>,
                            hipFuncAttributeMaxDynamicSharedMemorySize, LDSB);
        hipFuncSetAttribute((const void*)gemm_i8_big<1>,
                            hipFuncAttributeMaxDynamicSharedMemorySize, LDSB);
        attr_done = true;
    }

    const int n4x = Bsz * DIN / 4, n4w1 = DH * DIN / 4, n4w2 = DOUT * DH / 4;
    quant_all_kernel<<<(n4x + n4w1 + n4w2) / 256, 256, 0, stream>>>(
        x, (uint32_t*)xh, (uint32_t*)xl, w1, (uint32_t*)w1m, w2, (uint32_t*)w2m,
        n4x, n4w1, n4w2);

    // fc1: h = relu(q8(x8 @ w1q^T)) -> packed hi/lo  [8192,4096]
    gemm_i8_big<0><<<dim3(2048), 256, LDSB, stream>>>(xh, xl, w1m, (void*)hh, (void*)hl, Bsz, DH, DIN);

    // fc2: out = q8(h @ w2q^T)  [8192,1024] fp32
    gemm_i8_big<1><<<dim3(512), 256, LDSB, stream>>>(hh, hl, w2m, (void*)out, nullptr, Bsz, DOUT, DH);
}

// Round 6
// 253.163 us; speedup vs baseline: 7.1279x; 1.0079x over previous
//
#include <hip/hip_runtime.h>
#include <stdint.h>
#include <stddef.h>

typedef int v4i  __attribute__((ext_vector_type(4)));
typedef int v16i __attribute__((ext_vector_type(16)));

#define KCH  128                 // K-chunk per LDS buffer (8 granules of 16 B per row)
#define BUFB (128 * 128)         // 16 KB per buffer: [row][slot] 16B units
#define NBUF 3                   // triple buffer: stage c+2 during chunk c
#define LDSB (NBUF * BUFB)       // 48 KB -> 2 blocks/CU (96 KB of 160)

#define FENCE() asm volatile("" ::: "memory")

// async global->LDS, 16B per lane.
__device__ __forceinline__ void gl_lds16(const uint8_t* g, uint8_t* l) {
    __builtin_amdgcn_global_load_lds(
        (const __attribute__((address_space(1))) uint32_t*)g,
        (__attribute__((address_space(3))) uint32_t*)l,
        16, 0, 0);
}

// Software q8: EXACT reference semantics (floor(log2), clamp[-6,8], half-even, sat 448).
__device__ __forceinline__ float q8f(float v) {
    float a = fabsf(v);
    int e = (int)(__float_as_uint(a) >> 23) - 127;
    e = e < -6 ? -6 : (e > 8 ? 8 : e);
    float step  = __uint_as_float((uint32_t)(e - 3 + 127) << 23);  // 2^(e-3)
    float rstep = __uint_as_float((uint32_t)(3 - e + 127) << 23);  // 2^(3-e)
    float q = fminf(rintf(a * rstep) * step, 448.0f);
    return v < 0.0f ? -q : q;
}
__device__ __forceinline__ int qm(float v) {  // q8 value * 512 (exact int)
    return (int)rintf(q8f(v) * 512.0f);
}

// integer round-half-even shift: RNE(a / 2^s), a >= 0, s >= 1
__device__ __forceinline__ uint32_t rne_sh(uint32_t a, int s) {
    uint32_t t = a >> s;
    uint32_t rem = a & ((1u << s) - 1u);
    uint32_t half = 1u << (s - 1);
    t += (rem > half) || (rem == half && (t & 1u));
    return t;
}

// Fused quant. x is written in PACKED fragment order:
//   addr(r,g,b) = ((r>>5)*(K/16) + g)*512 + (r&31)*16 + b   (K=1024, 64 granules)
// so the GEMM's A-loads are lane-linear 1KB bursts. w1/w2 stay row-major.
__global__ __launch_bounds__(256) void quant_all_kernel(
    const float* __restrict__ x,  uint32_t* __restrict__ xh, uint32_t* __restrict__ xl,
    const float* __restrict__ w1, uint32_t* __restrict__ w1m,
    const float* __restrict__ w2, uint32_t* __restrict__ w2m,
    int n4x, int n4w1, int n4w2) {
    int i = blockIdx.x * 256 + threadIdx.x;
    if (i < n4x) {
        float4 v = ((const float4*)x)[i];
        int m0 = qm(v.x), m1 = qm(v.y), m2 = qm(v.z), m3 = qm(v.w);
        uint32_t h = ((uint32_t)((m0 >> 5) & 0xff)) | ((uint32_t)((m1 >> 5) & 0xff) << 8) |
                     ((uint32_t)((m2 >> 5) & 0xff) << 16) | ((uint32_t)((m3 >> 5) & 0xff) << 24);
        uint32_t l = ((uint32_t)(m0 & 31)) | ((uint32_t)(m1 & 31) << 8) |
                     ((uint32_t)(m2 & 31) << 16) | ((uint32_t)(m3 & 31) << 24);
        int r = i >> 8, c4 = i & 255;                     // K/4 = 256 float4 per row
        int pi = ((r >> 5) * 64 + (c4 >> 2)) * 128 + (r & 31) * 4 + (c4 & 3);
        xh[pi] = h;
        xl[pi] = l;
    } else if (i < n4x + n4w1) {
        int j = i - n4x;
        float4 v = ((const float4*)w1)[j];
        w1m[j] = ((uint32_t)(qm(v.x) & 0xff)) | ((uint32_t)(qm(v.y) & 0xff) << 8) |
                 ((uint32_t)(qm(v.z) & 0xff) << 16) | ((uint32_t)(qm(v.w) & 0xff) << 24);
    } else if (i < n4x + n4w1 + n4w2) {
        int j = i - n4x - n4w1;
        float4 v = ((const float4*)w2)[j];
        w2m[j] = ((uint32_t)(qm(v.x) & 0xff)) | ((uint32_t)(qm(v.y) & 0xff) << 8) |
                 ((uint32_t)(qm(v.z) & 0xff) << 16) | ((uint32_t)(qm(v.w) & 0xff) << 24);
    }
}

// Stage one 128-row x 128-B K-chunk of B into LDS [row][slot], slot = g ^ (row&7).
// Per inst: 8 consecutive rows, 8 fully-used 128B segments. 4 waves, 4 insts each.
__device__ __forceinline__ void stage_chunk(
    const uint8_t* __restrict__ Bm, uint8_t* dst,
    int bn, int K, int kc, int wave, int lane) {
    const int r0 = lane >> 3;      // 0..7: row within the 8-row group
    const int sl = lane & 7;       // destination slot
#pragma unroll
    for (int s = 0; s < 4; ++s) {
        const int qd  = wave * 4 + s;          // 8-row group index (0..15)
        const int row = qd * 8 + r0;
        const int g   = sl ^ r0;               // source granule: slot ^ (row&7)
        gl_lds16(Bm + (size_t)(bn * 128 + row) * K + kc + g * 16,
                 dst + qd * 1024 + lane * 16);
    }
}

// C = (32*Ah + Al) * Bm^T * 2^-18, exact i32 via mfma_i32_32x32x32_i8.
// A is PACKED (fragment-order): per-t load = base + t*1024 + lane*16 (lane-linear).
// 256 thr = 4 waves, block tile 128x128, wave tile 32x128, 2 blocks/CU.
//
// Round-6 K-loop: COUNTED-VMCNT PIPELINE (T3+T4 core), no drain ever.
// Rounds 0-5 all pinned at ~90us/33% MfmaUtil regardless of occupancy, L2
// locality, or vmem issue order -> the invariant was __syncthreads' implied
// s_waitcnt vmcnt(0) draining the staging queue every chunk (the documented
// m97-structure stall). Now:
//  - triple-buffered LDS, stage chunk c+2 during chunk c (full-chunk latency cover)
//  - raw s_barrier (no compiler drain), memory fences pin issue order
//  - per-wave FIFO per chunk: [A burst x8][gl_lds stage(c+2) x4]; consuming the
//    last A pair waits vmcnt(4) -> stage(c+1) retires as a side effect during
//    chunk c, so at the top-of-chunk-(c+1) barrier every wave's stage is landed
//    WITHOUT any instruction ever waiting on an in-flight DMA.
// Correctness invariant (WAR on LDS): stage(c+2) writes buf[(c+2)%3] ==
// buf[(c-1)%3], whose readers (chunk c-1) all passed the top-of-c barrier
// before any of these gl_lds are issued.
//
// 1-D grid, XCD swizzle (bijective for 2048/512 blocks):
//   bm = (bid&7)*8 + (bid>>3)&7,  bn = (bid>>9)*8 + (bid>>6)&7
//
// EPI=0: q8+ReLU -> hi/lo planes written PACKED (K=N for next layer). EPI=1: fp32 row-major.
template <int EPI>
__global__ __launch_bounds__(256, 2) void gemm_i8_big(
    const uint8_t* __restrict__ Ah, const uint8_t* __restrict__ Al,
    const uint8_t* __restrict__ Bm,
    void* __restrict__ Ch, void* __restrict__ Cl,
    int M, int N, int K) {
    extern __shared__ uint8_t sB[];  // NBUF x BUFB

    const int tid  = threadIdx.x;
    const int lane = tid & 63;
    const int wave = tid >> 6;     // 4 waves = 4 row strips
    const int col  = lane & 31;
    const int kh   = lane >> 5;
    const int x7   = col & 7;

    const int bid = blockIdx.x;
    const int bm  = ((bid & 7) << 3) | ((bid >> 3) & 7);
    const int bn  = (((bid >> 9) << 3) | ((bid >> 6) & 7));

    v16i acc[2][4];
#pragma unroll
    for (int p = 0; p < 2; ++p)
#pragma unroll
        for (int j = 0; j < 4; ++j) acc[p][j] = (v16i)0;

    // packed A: row-block (bm*4 + wave), sequential 1KB per t-step across all K
    const size_t abase = (size_t)(bm * 4 + wave) * (K >> 4) * 512 + lane * 16;
    const uint8_t* pAh = Ah + abase;
    const uint8_t* pAl = Al + abase;

    int rowoff[4];
#pragma unroll
    for (int j = 0; j < 4; ++j) rowoff[j] = (j * 32 + col) * 128;

    const int NC = K / KCH;      // 8 (fc1) / 32 (fc2)

    // prologue: stage chunks 0 and 1; wait only for stage(0) (stage(1) stays in flight)
    stage_chunk(Bm, sB, bn, K, 0, wave, lane);
    stage_chunk(Bm, sB + BUFB, bn, K, KCH, wave, lane);
    FENCE();
    asm volatile("s_waitcnt vmcnt(4)" ::: "memory");

    for (int c = 0; c < NC; ++c) {
        // all waves done reading buf[(c-1)%3]; own stage(c) retired via A-consume FIFO
        FENCE();
        __builtin_amdgcn_s_barrier();
        FENCE();

        const uint8_t* buf  = sB + (c % NBUF) * BUFB;
        const uint8_t* pAhc = pAh + (size_t)c * 4096;   // 4 t-steps x 1KB
        const uint8_t* pAlc = pAl + (size_t)c * 4096;

        // A burst: all 8 loads for this chunk, BEFORE the staging gl_lds,
        // so A-consume waits never touch the DMA queue (worst wait: vmcnt(4)).
        v4i ab[8];
#pragma unroll
        for (int u = 0; u < 4; ++u) {
            ab[2 * u]     = *(const v4i*)(pAhc + u * 1024);
            ab[2 * u + 1] = *(const v4i*)(pAlc + u * 1024);
        }
        FENCE();
        if (c + 2 < NC)
            stage_chunk(Bm, sB + ((c + 2) % NBUF) * BUFB, bn, K, (c + 2) * KCH, wave, lane);
        FENCE();

#pragma unroll
        for (int t = 0; t < 4; ++t) {
            const int slot = ((2 * t + kh) ^ x7);
            v4i b[4];
#pragma unroll
            for (int j = 0; j < 4; ++j)
                b[j] = *(const v4i*)(buf + rowoff[j] + slot * 16);
#pragma unroll
            for (int j = 0; j < 4; ++j) {
                acc[0][j] = __builtin_amdgcn_mfma_i32_32x32x32_i8(ab[2 * t],     b[j], acc[0][j], 0, 0, 0);
                acc[1][j] = __builtin_amdgcn_mfma_i32_32x32x32_i8(ab[2 * t + 1], b[j], acc[1][j], 0, 0, 0);
            }
        }
    }

    // C/D layout (32x32): col = lane&31, row = (reg&3) + 8*(reg>>2) + 4*(lane>>5)
    const int Gn = N >> 4;  // granules per output row (packed dest, EPI=0)
    const int rb = bm * 4 + wave;
#pragma unroll
    for (int j = 0; j < 4; ++j) {
        const int colk = bn * 128 + j * 32 + col;
#pragma unroll
        for (int reg = 0; reg < 16; ++reg) {
            int mt = acc[0][j][reg] * 32 + acc[1][j][reg];  // exact, |mt| < 2^24
            const int rw = 4 * kh + (reg & 3) + 8 * (reg >> 2);  // row within 32
            if (EPI == 0) {
                uint8_t hb = 0, lb = 0;
                if (mt > 0) {
                    int s = 28 - __builtin_clz((uint32_t)mt);
                    if (s < 9) s = 9;
                    int mh = (int)(rne_sh((uint32_t)mt, s) << (s - 9));
                    hb = (uint8_t)(mh >> 5);
                    lb = (uint8_t)(mh & 31);
                }
                size_t pa = ((size_t)rb * Gn + (colk >> 4)) * 512 + rw * 16 + (colk & 15);
                ((uint8_t*)Ch)[pa] = hb;
                ((uint8_t*)Cl)[pa] = lb;
            } else {
                uint32_t a = mt < 0 ? (uint32_t)(-mt) : (uint32_t)mt;
                float v = 0.0f;
                if (a) {
                    int s = 28 - __builtin_clz(a);
                    if (s < 9) s = 9;
                    v = (float)(rne_sh(a, s) << s) * 0x1p-18f;  // exact
                    if (mt < 0) v = -v;
                }
                ((float*)Ch)[(size_t)(rb * 32 + rw) * N + colk] = v;
            }
        }
    }
}

extern "C" void kernel_launch(void* const* d_in, const int* in_sizes, int n_in,
                              void* d_out, int out_size, void* d_ws, size_t ws_size,
                              hipStream_t stream) {
    const int Bsz = 8192, DIN = 1024, DH = 4096, DOUT = 1024;
    const float* x  = (const float*)d_in[0];
    const float* w1 = (const float*)d_in[1];
    const float* w2 = (const float*)d_in[2];
    float* out = (float*)d_out;

    uint8_t* ws  = (uint8_t*)d_ws;
    uint8_t* xh  = ws;                            //  8 MB (packed)
    uint8_t* xl  = xh  + (size_t)Bsz * DIN;       //  8 MB (packed)
    uint8_t* w1m = xl  + (size_t)Bsz * DIN;       //  4 MB
    uint8_t* w2m = w1m + (size_t)DH  * DIN;       //  4 MB
    uint8_t* hh  = w2m + (size_t)DOUT * DH;       // 32 MB (packed)
    uint8_t* hl  = hh  + (size_t)Bsz * DH;        // 32 MB (packed)

    static bool attr_done = false;
    if (!attr_done) {
        hipFuncSetAttribute((const void*)gemm_i8_big<0>,
                            hipFuncAttributeMaxDynamicSharedMemorySize, LDSB);
        hipFuncSetAttribute((const void*)gemm_i8_big<1>,
                            hipFuncAttributeMaxDynamicSharedMemorySize, LDSB);
        attr_done = true;
    }

    const int n4x = Bsz * DIN / 4, n4w1 = DH * DIN / 4, n4w2 = DOUT * DH / 4;
    quant_all_kernel<<<(n4x + n4w1 + n4w2) / 256, 256, 0, stream>>>(
        x, (uint32_t*)xh, (uint32_t*)xl, w1, (uint32_t*)w1m, w2, (uint32_t*)w2m,
        n4x, n4w1, n4w2);

    // fc1: h = relu(q8(x8 @ w1q^T)) -> packed hi/lo  [8192,4096]
    gemm_i8_big<0><<<dim3(2048), 256, LDSB, stream>>>(xh, xl, w1m, (void*)hh, (void*)hl, Bsz, DH, DIN);

    // fc2: out = q8(h @ w2q^T)  [8192,1024] fp32
    gemm_i8_big<1><<<dim3(512), 256, LDSB, stream>>>(hh, hl, w2m, (void*)out, nullptr, Bsz, DOUT, DH);
}

// Round 7
// 242.614 us; speedup vs baseline: 7.4378x; 1.0435x over previous
//
#include <hip/hip_runtime.h>
#include <stdint.h>
#include <stddef.h>

typedef int v4i  __attribute__((ext_vector_type(4)));
typedef int v16i __attribute__((ext_vector_type(16)));

#define KCH  256                 // K-chunk per LDS buffer (16 granules of 16 B)
#define BUFB (128 * 256)         // 32 KB per buffer: [row][slot] 16B units
#define LDSB (2 * BUFB)          // 64 KB -> 2 blocks/CU

// async global->LDS, 16B per lane.
__device__ __forceinline__ void gl_lds16(const uint8_t* g, uint8_t* l) {
    __builtin_amdgcn_global_load_lds(
        (const __attribute__((address_space(1))) uint32_t*)g,
        (__attribute__((address_space(3))) uint32_t*)l,
        16, 0, 0);
}

// Software q8: EXACT reference semantics (floor(log2), clamp[-6,8], half-even, sat 448).
__device__ __forceinline__ float q8f(float v) {
    float a = fabsf(v);
    int e = (int)(__float_as_uint(a) >> 23) - 127;
    e = e < -6 ? -6 : (e > 8 ? 8 : e);
    float step  = __uint_as_float((uint32_t)(e - 3 + 127) << 23);  // 2^(e-3)
    float rstep = __uint_as_float((uint32_t)(3 - e + 127) << 23);  // 2^(3-e)
    float q = fminf(rintf(a * rstep) * step, 448.0f);
    return v < 0.0f ? -q : q;
}
__device__ __forceinline__ int qm(float v) {  // q8 value * 512 (exact int)
    return (int)rintf(q8f(v) * 512.0f);
}

// integer round-half-even shift: RNE(a / 2^s), a >= 0, s >= 1
__device__ __forceinline__ uint32_t rne_sh(uint32_t a, int s) {
    uint32_t t = a >> s;
    uint32_t rem = a & ((1u << s) - 1u);
    uint32_t half = 1u << (s - 1);
    t += (rem > half) || (rem == half && (t & 1u));
    return t;
}

// Round-7 quant. x is written in PACKED fragment order:
//   addr(r,g,b) = ((r>>5)*(K/16) + g)*512 + (r&31)*16 + b   (K=1024, 64 granules)
// OLD mapping scattered 4B stores at 512B stride (16 lines touched per wave
// store, 16B used per line) -> partial-line write amplification; quant ran
// ~68us vs a 14us traffic roofline. NEW mapping: lane owns (row r, granule g)
// = 16 consecutive k-elements -> ONE 16B store; a wave covers 2 granules
// = 1KB CONTIGUOUS per store instruction. Reads: 4x16B per lane covering a
// full 64B line (line fully consumed across the 4 loads).
//   blocks [0, 2048):        x   (rowgroup = blk>>3, granules (blk&7)*8 + wave*2 + lane>>5)
//   blocks [2048, 6144):     w1  (row-major u32, already coalesced)
//   blocks [6144, 10240):    w2
__global__ __launch_bounds__(256) void quant_all_kernel(
    const float* __restrict__ x,  uint8_t* __restrict__ xh, uint8_t* __restrict__ xl,
    const float* __restrict__ w1, uint32_t* __restrict__ w1m,
    const float* __restrict__ w2, uint32_t* __restrict__ w2m) {
    const int blk = blockIdx.x;
    const int tid = threadIdx.x;
    if (blk < 2048) {
        const int wave = tid >> 6, lane = tid & 63;
        const int rg = blk >> 3;                                // 32-row group, 0..255
        const int g  = ((blk & 7) << 3) + wave * 2 + (lane >> 5); // granule 0..63
        const int r  = rg * 32 + (lane & 31);
        const float* px = x + (size_t)r * 1024 + g * 16;
        v4i hv, lv;
#pragma unroll
        for (int q = 0; q < 4; ++q) {
            float4 v = ((const float4*)px)[q];
            int m0 = qm(v.x), m1 = qm(v.y), m2 = qm(v.z), m3 = qm(v.w);
            hv[q] = (int)(((uint32_t)((m0 >> 5) & 0xff)) | ((uint32_t)((m1 >> 5) & 0xff) << 8) |
                          ((uint32_t)((m2 >> 5) & 0xff) << 16) | ((uint32_t)((m3 >> 5) & 0xff) << 24));
            lv[q] = (int)(((uint32_t)(m0 & 31)) | ((uint32_t)(m1 & 31) << 8) |
                          ((uint32_t)(m2 & 31) << 16) | ((uint32_t)(m3 & 31) << 24));
        }
        const size_t pa = ((size_t)rg * 64 + g) * 512 + (size_t)(lane & 31) * 16;
        *(v4i*)(xh + pa) = hv;
        *(v4i*)(xl + pa) = lv;
    } else if (blk < 2048 + 4096) {
        int j = (blk - 2048) * 256 + tid;        // over DH*DIN/4 = 1M float4
        float4 v = ((const float4*)w1)[j];
        w1m[j] = ((uint32_t)(qm(v.x) & 0xff)) | ((uint32_t)(qm(v.y) & 0xff) << 8) |
                 ((uint32_t)(qm(v.z) & 0xff) << 16) | ((uint32_t)(qm(v.w) & 0xff) << 24);
    } else {
        int j = (blk - 6144) * 256 + tid;        // over DOUT*DH/4 = 1M float4
        float4 v = ((const float4*)w2)[j];
        w2m[j] = ((uint32_t)(qm(v.x) & 0xff)) | ((uint32_t)(qm(v.y) & 0xff) << 8) |
                 ((uint32_t)(qm(v.z) & 0xff) << 16) | ((uint32_t)(qm(v.w) & 0xff) << 24);
    }
}

// Stage one K-chunk of B (row-major) into LDS [row][slot], slot = g ^ (row&15).
// Per inst: 4 consecutive rows, 16 fully-used lines. 4 waves, 8 insts each.
__device__ __forceinline__ void stage_chunk(
    const uint8_t* __restrict__ Bm, uint8_t* dst,
    int bn, int K, int kc, int wave, int lane) {
    const int r0 = lane >> 4;
    const int sl = lane & 15;
#pragma unroll
    for (int s = 0; s < 8; ++s) {
        const int qd  = wave * 8 + s;
        const int row = qd * 4 + r0;
        const int g   = sl ^ (row & 15);
        gl_lds16(Bm + (size_t)(bn * 128 + row) * K + kc + g * 16,
                 dst + qd * 1024 + lane * 16);
    }
}

// C = (32*Ah + Al) * Bm^T * 2^-18, exact i32 via mfma_i32_32x32x32_i8.
// A is PACKED (fragment-order): per-t load = base + t*1024 + lane*16 (lane-linear).
// 256 thr = 4 waves, block tile 128x128, wave tile 32x128, 2 blocks/CU.
// (Round-5 K-loop, best measured at 89.4-89.7us: half-chunk A bursts.)
//
// 1-D grid, XCD swizzle (bijective for 2048/512 blocks):
//   bm = (bid&7)*8 + (bid>>3)&7,  bn = (bid>>9)*8 + (bid>>6)&7
//
// EPI=0: q8+ReLU -> hi/lo planes written PACKED (K=N for next layer). EPI=1: fp32 row-major.
template <int EPI>
__global__ __launch_bounds__(256, 2) void gemm_i8_big(
    const uint8_t* __restrict__ Ah, const uint8_t* __restrict__ Al,
    const uint8_t* __restrict__ Bm,
    void* __restrict__ Ch, void* __restrict__ Cl,
    int M, int N, int K) {
    extern __shared__ uint8_t sB[];  // 2 x BUFB

    const int tid  = threadIdx.x;
    const int lane = tid & 63;
    const int wave = tid >> 6;     // 4 waves = 4 row strips
    const int col  = lane & 31;
    const int kh   = lane >> 5;
    const int xm   = col & 15;

    const int bid = blockIdx.x;
    const int bm  = ((bid & 7) << 3) | ((bid >> 3) & 7);
    const int bn  = (((bid >> 9) << 3) | ((bid >> 6) & 7));

    v16i acc[2][4];
#pragma unroll
    for (int p = 0; p < 2; ++p)
#pragma unroll
        for (int j = 0; j < 4; ++j) acc[p][j] = (v16i)0;

    // packed A: row-block (bm*4 + wave), sequential 1KB per t-step across all K
    const size_t abase = (size_t)(bm * 4 + wave) * (K >> 4) * 512 + lane * 16;
    const uint8_t* pAh = Ah + abase;
    const uint8_t* pAl = Al + abase;

    int rowoff[4];
#pragma unroll
    for (int j = 0; j < 4; ++j) rowoff[j] = (j * 32 + col) * 256;

    const int NC = K / KCH;
    stage_chunk(Bm, sB, bn, K, 0, wave, lane);

    for (int c = 0; c < NC; ++c) {
        __syncthreads();  // stage(c) complete
        const uint8_t* buf  = sB + (c & 1) * BUFB;
        const uint8_t* pAhc = pAh + (size_t)c * 8192;   // 8 t-steps x 1KB
        const uint8_t* pAlc = pAl + (size_t)c * 8192;

        v4i ab[8];
        // burst 0: A pairs for t = 0..3, issued BEFORE the staging gl_lds
#pragma unroll
        for (int u = 0; u < 4; ++u) {
            ab[2 * u]     = *(const v4i*)(pAhc + u * 1024);
            ab[2 * u + 1] = *(const v4i*)(pAlc + u * 1024);
        }
        if (c + 1 < NC)
            stage_chunk(Bm, sB + ((c + 1) & 1) * BUFB, bn, K, (c + 1) * KCH, wave, lane);

        // half 0: t = 0..3
#pragma unroll
        for (int u = 0; u < 4; ++u) {
            const int t = u;
            const int slot = ((2 * t + kh) & 15) ^ xm;
            v4i b[4];
#pragma unroll
            for (int j = 0; j < 4; ++j)
                b[j] = *(const v4i*)(buf + rowoff[j] + slot * 16);
#pragma unroll
            for (int j = 0; j < 4; ++j) {
                acc[0][j] = __builtin_amdgcn_mfma_i32_32x32x32_i8(ab[2 * u],     b[j], acc[0][j], 0, 0, 0);
                acc[1][j] = __builtin_amdgcn_mfma_i32_32x32x32_i8(ab[2 * u + 1], b[j], acc[1][j], 0, 0, 0);
            }
        }

        // burst 1: A pairs for t = 4..7 (after gl_lds in FIFO -> consuming them
        // forces gl_lds retirement only with ~4 t-steps of cover)
#pragma unroll
        for (int u = 0; u < 4; ++u) {
            ab[2 * u]     = *(const v4i*)(pAhc + (4 + u) * 1024);
            ab[2 * u + 1] = *(const v4i*)(pAlc + (4 + u) * 1024);
        }

        // half 1: t = 4..7
#pragma unroll
        for (int u = 0; u < 4; ++u) {
            const int t = 4 + u;
            const int slot = ((2 * t + kh) & 15) ^ xm;
            v4i b[4];
#pragma unroll
            for (int j = 0; j < 4; ++j)
                b[j] = *(const v4i*)(buf + rowoff[j] + slot * 16);
#pragma unroll
            for (int j = 0; j < 4; ++j) {
                acc[0][j] = __builtin_amdgcn_mfma_i32_32x32x32_i8(ab[2 * u],     b[j], acc[0][j], 0, 0, 0);
                acc[1][j] = __builtin_amdgcn_mfma_i32_32x32x32_i8(ab[2 * u + 1], b[j], acc[1][j], 0, 0, 0);
            }
        }
    }

    // C/D layout (32x32): col = lane&31, row = (reg&3) + 8*(reg>>2) + 4*(lane>>5)
    const int Gn = N >> 4;  // granules per output row (packed dest, EPI=0)
    const int rb = bm * 4 + wave;
#pragma unroll
    for (int j = 0; j < 4; ++j) {
        const int colk = bn * 128 + j * 32 + col;
#pragma unroll
        for (int reg = 0; reg < 16; ++reg) {
            int mt = acc[0][j][reg] * 32 + acc[1][j][reg];  // exact, |mt| < 2^24
            const int rw = 4 * kh + (reg & 3) + 8 * (reg >> 2);  // row within 32
            if (EPI == 0) {
                uint8_t hb = 0, lb = 0;
                if (mt > 0) {
                    int s = 28 - __builtin_clz((uint32_t)mt);
                    if (s < 9) s = 9;
                    int mh = (int)(rne_sh((uint32_t)mt, s) << (s - 9));
                    hb = (uint8_t)(mh >> 5);
                    lb = (uint8_t)(mh & 31);
                }
                size_t pa = ((size_t)rb * Gn + (colk >> 4)) * 512 + rw * 16 + (colk & 15);
                ((uint8_t*)Ch)[pa] = hb;
                ((uint8_t*)Cl)[pa] = lb;
            } else {
                uint32_t a = mt < 0 ? (uint32_t)(-mt) : (uint32_t)mt;
                float v = 0.0f;
                if (a) {
                    int s = 28 - __builtin_clz(a);
                    if (s < 9) s = 9;
                    v = (float)(rne_sh(a, s) << s) * 0x1p-18f;  // exact
                    if (mt < 0) v = -v;
                }
                ((float*)Ch)[(size_t)(rb * 32 + rw) * N + colk] = v;
            }
        }
    }
}

extern "C" void kernel_launch(void* const* d_in, const int* in_sizes, int n_in,
                              void* d_out, int out_size, void* d_ws, size_t ws_size,
                              hipStream_t stream) {
    const int Bsz = 8192, DIN = 1024, DH = 4096, DOUT = 1024;
    const float* x  = (const float*)d_in[0];
    const float* w1 = (const float*)d_in[1];
    const float* w2 = (const float*)d_in[2];
    float* out = (float*)d_out;

    uint8_t* ws  = (uint8_t*)d_ws;
    uint8_t* xh  = ws;                            //  8 MB (packed)
    uint8_t* xl  = xh  + (size_t)Bsz * DIN;       //  8 MB (packed)
    uint8_t* w1m = xl  + (size_t)Bsz * DIN;       //  4 MB
    uint8_t* w2m = w1m + (size_t)DH  * DIN;       //  4 MB
    uint8_t* hh  = w2m + (size_t)DOUT * DH;       // 32 MB (packed)
    uint8_t* hl  = hh  + (size_t)Bsz * DH;        // 32 MB (packed)

    static bool attr_done = false;
    if (!attr_done) {
        hipFuncSetAttribute((const void*)gemm_i8_big<0>,
                            hipFuncAttributeMaxDynamicSharedMemorySize, LDSB);
        hipFuncSetAttribute((const void*)gemm_i8_big<1>,
                            hipFuncAttributeMaxDynamicSharedMemorySize, LDSB);
        attr_done = true;
    }

    // quant: 2048 blocks for x (coalesced packed writes) + 4096 (w1) + 4096 (w2)
    quant_all_kernel<<<10240, 256, 0, stream>>>(
        x, xh, xl, w1, (uint32_t*)w1m, w2, (uint32_t*)w2m);

    // fc1: h = relu(q8(x8 @ w1q^T)) -> packed hi/lo  [8192,4096]
    gemm_i8_big<0><<<dim3(2048), 256, LDSB, stream>>>(xh, xl, w1m, (void*)hh, (void*)hl, Bsz, DH, DIN);

    // fc2: out = q8(h @ w2q^T)  [8192,1024] fp32
    gemm_i8_big<1><<<dim3(512), 256, LDSB, stream>>>(hh, hl, w2m, (void*)out, nullptr, Bsz, DOUT, DH);
}